// Round 11
// baseline (1184.930 us; speedup 1.0000x reference)
//
#include <hip/hip_runtime.h>
#include <math.h>

#define H 128

typedef __attribute__((ext_vector_type(8))) short short8;
typedef __attribute__((ext_vector_type(4))) float f32x4;

static const int SRC_T_[7] = {0, 0, 1, 1, 1, 2, 2};
static const int DST_T_[7] = {0, 1, 0, 1, 2, 1, 2};

__device__ __forceinline__ float eluf(float x) {
    return x > 0.f ? x : (__expf(x) - 1.f);
}
__device__ __forceinline__ unsigned short f2bf(float x) {  // RNE f32->bf16
    union { float f; unsigned int u; } v; v.f = x;
    unsigned int r = v.u + 0x7fffu + ((v.u >> 16) & 1u);
    return (unsigned short)(r >> 16);
}
__device__ __forceinline__ float bf2f(unsigned int u) {
    union { unsigned int u; float f; } v; v.u = u << 16;
    return v.f;
}

// ---------------------------------------------------------------------------
// hb[t] = bf16(elu(x @ W + b)); x:[n,64], W:[64,128]
__global__ __launch_bounds__(128) void k_input_linear(
    const float* __restrict__ x, const float* __restrict__ W,
    const float* __restrict__ b, unsigned short* __restrict__ hb, int n)
{
    __shared__ float Ws[64 * H];
    __shared__ float xs[16 * 64];
    __shared__ unsigned short os[16 * H];
    const int j = threadIdx.x;
    for (int i = j; i < 64 * H; i += 128) Ws[i] = W[i];
    const float bj = b[j];

    for (int r0 = blockIdx.x * 16; r0 < n; r0 += gridDim.x * 16) {
        const int nrows = min(16, n - r0);
        __syncthreads();
        for (int i = j; i < nrows * 64; i += 128) xs[i] = x[(size_t)r0 * 64 + i];
        __syncthreads();
        for (int i = 0; i < nrows; ++i) {
            float acc = bj;
#pragma unroll
            for (int k = 0; k < 64; k += 4) {
                float4 xv = *(const float4*)&xs[i * 64 + k];
                acc += xv.x * Ws[(k + 0) * H + j] + xv.y * Ws[(k + 1) * H + j]
                     + xv.z * Ws[(k + 2) * H + j] + xv.w * Ws[(k + 3) * H + j];
            }
            os[i * H + j] = f2bf(eluf(acc));
        }
        __syncthreads();
        uint2* d = (uint2*)&hb[(size_t)r0 * H];
        const uint2* s2 = (const uint2*)os;
        for (int i = j; i < nrows * 32; i += 128) d[i] = s2[i];
    }
}

// --------------------------- batched CSR build ------------------------------
struct CsrCtx {
    const int* src[7]; const int* dst[7]; const float* ea[7];
    int* csr_src[7]; uint2* csr_ea[7]; int* ptr[7];
    int* deg; int* cursor; int* bsum;
    int eOff[8];
    int bOff[8];
    int nd[7];
};

__global__ __launch_bounds__(256) void k_hist_all(CsrCtx C, int Etot)
{
    for (int e = blockIdx.x * 256 + threadIdx.x; e < Etot; e += gridDim.x * 256) {
        int r = 0;
        while (e >= C.eOff[r + 1]) ++r;
        const int le = e - C.eOff[r];
        atomicAdd(&C.deg[(C.bOff[r] << 8) + C.dst[r][le]], 1);
    }
}

__global__ __launch_bounds__(256) void k_scan_partial_all(CsrCtx C)
{
    __shared__ int s[256];
    const int b = blockIdx.x;
    int r = 0;
    while (b >= C.bOff[r + 1]) ++r;
    const int lb = b - C.bOff[r];
    const int tid = threadIdx.x;
    const int idx = lb * 256 + tid;
    s[tid] = idx < C.nd[r] ? C.deg[(C.bOff[r] << 8) + idx] : 0;
    __syncthreads();
    for (int off = 128; off > 0; off >>= 1) {
        if (tid < off) s[tid] += s[tid + off];
        __syncthreads();
    }
    if (tid == 0) C.bsum[b] = s[0];
}

__global__ __launch_bounds__(512) void k_scan_mid_all(CsrCtx C)
{
    __shared__ int s[512];
    const int r = blockIdx.x;
    const int nb = C.bOff[r + 1] - C.bOff[r];
    const int tid = threadIdx.x;
    const int v = tid < nb ? C.bsum[C.bOff[r] + tid] : 0;
    s[tid] = v;
    __syncthreads();
    for (int off = 1; off < 512; off <<= 1) {
        int t = (tid >= off) ? s[tid - off] : 0;
        __syncthreads();
        s[tid] += t;
        __syncthreads();
    }
    if (tid < nb) C.bsum[C.bOff[r] + tid] = s[tid] - v;
    if (tid == nb - 1) C.ptr[r][C.nd[r]] = s[tid];
}

__global__ __launch_bounds__(256) void k_scan_final_all(CsrCtx C)
{
    __shared__ int s[256];
    const int b = blockIdx.x;
    int r = 0;
    while (b >= C.bOff[r + 1]) ++r;
    const int lb = b - C.bOff[r];
    const int tid = threadIdx.x;
    const int idx = lb * 256 + tid;
    const int v = idx < C.nd[r] ? C.deg[(C.bOff[r] << 8) + idx] : 0;
    s[tid] = v;
    __syncthreads();
    for (int off = 1; off < 256; off <<= 1) {
        int t = (tid >= off) ? s[tid - off] : 0;
        __syncthreads();
        s[tid] += t;
        __syncthreads();
    }
    if (idx < C.nd[r]) {
        const int excl = s[tid] - v + C.bsum[b];
        C.ptr[r][idx] = excl;
        C.cursor[(C.bOff[r] << 8) + idx] = excl;
    }
}

__global__ __launch_bounds__(256) void k_scatter_all(CsrCtx C, int Etot)
{
    for (int e = blockIdx.x * 256 + threadIdx.x; e < Etot; e += gridDim.x * 256) {
        int r = 0;
        while (e >= C.eOff[r + 1]) ++r;
        const int le = e - C.eOff[r];
        const int d = C.dst[r][le];
        const int pos = atomicAdd(&C.cursor[(C.bOff[r] << 8) + d], 1);
        C.csr_src[r][pos] = C.src[r][le];
        const float* eap = C.ea[r] + (size_t)3 * le;
        uint2 p;
        p.x = (unsigned int)f2bf(eap[0]) | ((unsigned int)f2bf(eap[1]) << 16);
        p.y = (unsigned int)f2bf(eap[2]);
        C.csr_ea[r][pos] = p;
    }
}

// ---------------------------------------------------------------------------
// Weight prep: W1,W2 [21][128k][128c] f32 -> wp [21][2][128c][128k] bf16
__global__ __launch_bounds__(256) void k_wprep(
    const float* __restrict__ W1, const float* __restrict__ W2,
    unsigned short* __restrict__ wp, int total)
{
    for (int i = blockIdx.x * 256 + threadIdx.x; i < total; i += gridDim.x * 256) {
        int lr = i >> 14, rem = i & 16383;
        int c = rem >> 7, k = rem & 127;
        wp[(size_t)(lr * 2 + 0) * 16384 + rem] = f2bf(W1[(size_t)lr * 16384 + k * H + c]);
        wp[(size_t)(lr * 2 + 1) * 16384 + rem] = f2bf(W2[(size_t)lr * 16384 + k * H + c]);
    }
}

// ---------------------------------------------------------------------------
// Fused per-layer kernel: gather-aggregate + 2-GEMM MLP, one dispatch.
//   z_rel = hin_dst + sum_e relu(hin_src + ea@eW + eb)  (built in LDS)
//   hnew  = elu( sum_rel (relu(z_rel@W1*bn+..)@W2 + b2) + hin_dst )
// hin/hout ping-pong (no intra-dispatch read/write hazard).
struct LayerCtx {
    const int* ptr[3][3];
    const int* csr_src[3][3];
    const uint2* csr_ea[3][3];
    int srcOffH[3][3];   // source type offset * H
    int rel[3][3];       // relation index (0..6)
    int nrel[3];
    int gend[3];
    int noffH[3];
    int n[3];
};

__global__ __launch_bounds__(512, 4) void k_layer_all(
    LayerCtx L, const unsigned short* __restrict__ hin,
    unsigned short* __restrict__ hout, float* __restrict__ fout,
    const unsigned short* __restrict__ wprep,
    const float* __restrict__ eWg, const float* __restrict__ ebg,
    const float* __restrict__ b1g, const float* __restrict__ g1g,
    const float* __restrict__ be1g, const float* __restrict__ b2g,
    int l, int fin)
{
    __shared__ unsigned short zt[128 * H];   // 32 KB, XOR-swizzled
    __shared__ unsigned short a1t[128 * H];  // 32 KB, XOR-swizzled

    const int b = blockIdx.x;
    const int t = (b >= L.gend[0] ? 1 : 0) + (b >= L.gend[1] ? 1 : 0);
    const int lb = b - (t == 0 ? 0 : L.gend[t - 1]);
    const int n = L.n[t];
    const int nrel = L.nrel[t];
    const unsigned short* hinp = hin + (size_t)L.noffH[t];  // dst rows

    const int tid = threadIdx.x;
    const int lane = tid & 63;
    const int wave = tid >> 6;
    const int wr = wave >> 2;
    const int wc = wave & 3;
    const int l15 = lane & 15;
    const int lq  = lane >> 4;
    const int c0 = wc * 32 + l15;
    const int t2 = lane << 1;   // gather: 2 cols per lane

    const int r0 = lb * 128;
    const int rows = min(128, n - r0);

    const float bn_inv = 0.99999500003749977f;
    const f32x4 Z4 = {0.f, 0.f, 0.f, 0.f};
    f32x4 acc2[4][2];
#pragma unroll
    for (int rb = 0; rb < 4; ++rb)
#pragma unroll
        for (int nf = 0; nf < 2; ++nf) acc2[rb][nf] = Z4;
    float b2s0 = 0.f, b2s1 = 0.f;

    for (int rl = 0; rl < nrel; ++rl) {
        const int lr = l * 7 + L.rel[t][rl];
        const unsigned short* wp = wprep + (size_t)lr * 32768;

        // ---- gather phase: this wave builds z rows [d0,dend) into zt ----
        {
            const int* __restrict__ ptr = L.ptr[t][rl];
            const int* __restrict__ cs = L.csr_src[t][rl];
            const uint2* __restrict__ ce = L.csr_ea[t][rl];
            const unsigned short* __restrict__ hs = hin + (size_t)L.srcOffH[t][rl];
            const float* eWr = eWg + (size_t)lr * 3 * H;
            const float* ebr = ebg + (size_t)lr * H;
            const float w00 = eWr[t2],         w01 = eWr[t2 + 1];
            const float w10 = eWr[H + t2],     w11 = eWr[H + t2 + 1];
            const float w20 = eWr[2 * H + t2], w21 = eWr[2 * H + t2 + 1];
            const float b0 = ebr[t2], b1e = ebr[t2 + 1];
            unsigned int* __restrict__ ztu = (unsigned int*)zt;

            const int d0 = r0 + wave * 16;
            const int dend = min(d0 + 16, n);
            int p1v = (d0 < dend) ? ptr[d0] : 0;
            for (int d = d0; d < dend; ++d) {
                const int p0 = p1v;
                p1v = ptr[d + 1];
                const unsigned int hdv = ((const unsigned int*)&hinp[(size_t)d * H])[lane];
                float acc0 = bf2f(hdv & 0xffffu);
                float acc1 = bf2f(hdv >> 16);
                int i = p0;
                for (; i + 1 < p1v; i += 2) {
                    const int s0 = cs[i], s1 = cs[i + 1];
                    const uint2 e0 = ce[i], e1 = ce[i + 1];
                    const unsigned int hv0 = ((const unsigned int*)&hs[(size_t)s0 * H])[lane];
                    const unsigned int hv1 = ((const unsigned int*)&hs[(size_t)s1 * H])[lane];
                    const float a00 = bf2f(e0.x & 0xffffu), a01 = bf2f(e0.x >> 16), a02 = bf2f(e0.y & 0xffffu);
                    const float a10 = bf2f(e1.x & 0xffffu), a11 = bf2f(e1.x >> 16), a12 = bf2f(e1.y & 0xffffu);
                    acc0 += fmaxf(bf2f(hv0 & 0xffffu) + a00 * w00 + a01 * w10 + a02 * w20 + b0, 0.f)
                          + fmaxf(bf2f(hv1 & 0xffffu) + a10 * w00 + a11 * w10 + a12 * w20 + b0, 0.f);
                    acc1 += fmaxf(bf2f(hv0 >> 16) + a00 * w01 + a01 * w11 + a02 * w21 + b1e, 0.f)
                          + fmaxf(bf2f(hv1 >> 16) + a10 * w01 + a11 * w11 + a12 * w21 + b1e, 0.f);
                }
                if (i < p1v) {
                    const int s = cs[i];
                    const uint2 ep = ce[i];
                    const float a0 = bf2f(ep.x & 0xffffu);
                    const float a1 = bf2f(ep.x >> 16);
                    const float a2 = bf2f(ep.y & 0xffffu);
                    const unsigned int hv = ((const unsigned int*)&hs[(size_t)s * H])[lane];
                    acc0 += fmaxf(bf2f(hv & 0xffffu) + a0 * w00 + a1 * w10 + a2 * w20 + b0, 0.f);
                    acc1 += fmaxf(bf2f(hv >> 16)     + a0 * w01 + a1 * w11 + a2 * w21 + b1e, 0.f);
                }
                // swizzled LDS store (uint idx XOR (row&7)<<2)
                ztu[(size_t)(d - r0) * 64 + (lane ^ ((d & 7) << 2))] =
                    (unsigned int)f2bf(acc0) | ((unsigned int)f2bf(acc1) << 16);
            }
            // zero-fill this wave's tail rows (masked later, keep MFMA clean)
            for (int d = (dend > d0 ? dend : d0); d < d0 + 16; ++d)
                ztu[(size_t)(d - r0) * 64 + lane] = 0;
        }

        // preload GEMM1 weight fragments + scalars (overlap with barrier)
        short8 w1f[2][4];
#pragma unroll
        for (int nf = 0; nf < 2; ++nf)
#pragma unroll
            for (int kc = 0; kc < 4; ++kc)
                w1f[nf][kc] = *(const short8*)&wp[(c0 + nf * 16) * H + kc * 32 + (lq << 3)];
        const float b1c0 = b1g[lr * H + c0],            b1c1 = b1g[lr * H + c0 + 16];
        const float sc0  = g1g[lr * H + c0] * bn_inv,   sc1  = g1g[lr * H + c0 + 16] * bn_inv;
        const float be0  = be1g[lr * H + c0],           be1v = be1g[lr * H + c0 + 16];
        b2s0 += b2g[lr * H + c0]; b2s1 += b2g[lr * H + c0 + 16];

        __syncthreads();  // A: zt ready

        // ---- GEMM1: zt @ W1 ----
        f32x4 acc1[4][2];
#pragma unroll
        for (int rb = 0; rb < 4; ++rb)
#pragma unroll
            for (int nf = 0; nf < 2; ++nf) acc1[rb][nf] = Z4;
#pragma unroll
        for (int kc = 0; kc < 4; ++kc) {
            const int kb = kc * 32 + (lq << 3);
            short8 af[4];
#pragma unroll
            for (int rb = 0; rb < 4; ++rb) {
                const int row = wr * 64 + rb * 16 + l15;
                af[rb] = *(const short8*)&zt[row * H + (kb ^ ((row & 7) << 3))];
            }
#pragma unroll
            for (int rb = 0; rb < 4; ++rb)
#pragma unroll
                for (int nf = 0; nf < 2; ++nf)
                    acc1[rb][nf] = __builtin_amdgcn_mfma_f32_16x16x32_bf16(
                        af[rb], w1f[nf][kc], acc1[rb][nf], 0, 0, 0);
        }
        // epilogue1: BN+ReLU -> a1t (swizzled)
#pragma unroll
        for (int rb = 0; rb < 4; ++rb)
#pragma unroll
            for (int nf = 0; nf < 2; ++nf) {
                const int col = c0 + nf * 16;
                const float b1c = nf == 0 ? b1c0 : b1c1;
                const float scv = nf == 0 ? sc0 : sc1;
                const float bev = nf == 0 ? be0 : be1v;
#pragma unroll
                for (int rg = 0; rg < 4; ++rg) {
                    const int row = wr * 64 + rb * 16 + (lq << 2) + rg;
                    float v = fmaxf((acc1[rb][nf][rg] + b1c) * scv + bev, 0.f);
                    a1t[row * H + (col ^ ((row & 7) << 3))] = f2bf(v);
                }
            }
        __syncthreads();  // B: a1t ready; zt dead

        // ---- GEMM2: a1t @ W2, C chained in acc2 ----
#pragma unroll
        for (int kc = 0; kc < 4; ++kc) {
            const int kb = kc * 32 + (lq << 3);
            short8 af[4], wf[2];
#pragma unroll
            for (int rb = 0; rb < 4; ++rb) {
                const int row = wr * 64 + rb * 16 + l15;
                af[rb] = *(const short8*)&a1t[row * H + (kb ^ ((row & 7) << 3))];
            }
#pragma unroll
            for (int nf = 0; nf < 2; ++nf)
                wf[nf] = *(const short8*)&wp[16384 + (c0 + nf * 16) * H + kb];
#pragma unroll
            for (int rb = 0; rb < 4; ++rb)
#pragma unroll
                for (int nf = 0; nf < 2; ++nf)
                    acc2[rb][nf] = __builtin_amdgcn_mfma_f32_16x16x32_bf16(
                        af[rb], wf[nf], acc2[rb][nf], 0, 0, 0);
        }
    }

    // ---- final epilogue: hnew = elu(acc2 + sum(b2) + hin) ----
    if (fin) {
        float* foutp = fout + (size_t)L.noffH[t];
#pragma unroll
        for (int rb = 0; rb < 4; ++rb)
#pragma unroll
            for (int nf = 0; nf < 2; ++nf) {
                const int col = c0 + nf * 16;
                const float b2s = nf == 0 ? b2s0 : b2s1;
#pragma unroll
                for (int rg = 0; rg < 4; ++rg) {
                    const int row = wr * 64 + rb * 16 + (lq << 2) + rg;
                    if (row < rows) {
                        const size_t o = (size_t)(r0 + row) * H + col;
                        foutp[o] = eluf(acc2[rb][nf][rg] + b2s
                                        + bf2f((unsigned int)hinp[o]));
                    }
                }
            }
    } else {
        unsigned short* houtp = hout + (size_t)L.noffH[t];
        __syncthreads();  // all GEMM2 reads of a1t done
#pragma unroll
        for (int rb = 0; rb < 4; ++rb)
#pragma unroll
            for (int nf = 0; nf < 2; ++nf) {
                const int col = c0 + nf * 16;
                const float b2s = nf == 0 ? b2s0 : b2s1;
#pragma unroll
                for (int rg = 0; rg < 4; ++rg) {
                    const int row = wr * 64 + rb * 16 + (lq << 2) + rg;
                    if (row < rows) {
                        const size_t o = (size_t)(r0 + row) * H + col;
                        a1t[row * H + col] = f2bf(eluf(acc2[rb][nf][rg] + b2s
                                                       + bf2f((unsigned int)hinp[o])));
                    }
                }
            }
        __syncthreads();
        uint2* d = (uint2*)&houtp[(size_t)r0 * H];
        const uint2* s2 = (const uint2*)a1t;
        for (int idx = tid; idx < rows * 32; idx += 512) d[idx] = s2[idx];
    }
}

static inline int imin(int a, int b) { return a < b ? a : b; }
static inline size_t alignup(size_t x) { return (x + 255) & ~(size_t)255; }

extern "C" void kernel_launch(void* const* d_in, const int* in_sizes, int n_in,
                              void* d_out, int out_size, void* d_ws, size_t ws_size,
                              hipStream_t stream) {
    const float* xin[3] = {(const float*)d_in[0], (const float*)d_in[1], (const float*)d_in[2]};
    const int* src[7]; const int* dst[7]; const float* ea[7]; int E[7];
    for (int r = 0; r < 7; ++r) {
        src[r] = (const int*)d_in[3 + 3 * r];
        dst[r] = (const int*)d_in[4 + 3 * r];
        ea[r]  = (const float*)d_in[5 + 3 * r];
        E[r]   = in_sizes[3 + 3 * r];
    }
    const float* linW[3] = {(const float*)d_in[24], (const float*)d_in[26], (const float*)d_in[28]};
    const float* linb[3] = {(const float*)d_in[25], (const float*)d_in[27], (const float*)d_in[29]};
    const float* eW  = (const float*)d_in[30];
    const float* ebp = (const float*)d_in[31];
    const float* W1  = (const float*)d_in[32];
    const float* b1  = (const float*)d_in[33];
    const float* g1  = (const float*)d_in[34];
    const float* be1 = (const float*)d_in[35];
    const float* W2  = (const float*)d_in[36];
    const float* b2  = (const float*)d_in[37];

    const int NSn[3]  = {in_sizes[0] / 64, in_sizes[1] / 64, in_sizes[2] / 64};
    const int NTOT = NSn[0] + NSn[1] + NSn[2];
    const int noff[3] = {0, NSn[0], NSn[0] + NSn[1]};

    float* fout = (float*)d_out;

    // prefixes
    int eOff[8]; eOff[0] = 0;
    for (int r = 0; r < 7; ++r) eOff[r + 1] = eOff[r] + E[r];
    const int Etot = eOff[7];
    int bOff[8]; bOff[0] = 0;
    for (int r = 0; r < 7; ++r) bOff[r + 1] = bOff[r] + (NSn[DST_T_[r]] + 255) / 256;

    // workspace carve-up
    char* wsb = (char*)d_ws;
    size_t off = 0;
    unsigned short* hb0 = (unsigned short*)(wsb + off); off = alignup(off + (size_t)NTOT * H * 2);
    unsigned short* hb1 = (unsigned short*)(wsb + off); off = alignup(off + (size_t)NTOT * H * 2);
    unsigned short* wprep = (unsigned short*)(wsb + off); off = alignup(off + (size_t)21 * 32768 * 2);
    int* deg    = (int*)(wsb + off); off = alignup(off + (size_t)bOff[7] * 256 * 4);
    int* cursor = (int*)(wsb + off); off = alignup(off + (size_t)bOff[7] * 256 * 4);
    int* bsum   = (int*)(wsb + off); off = alignup(off + (size_t)bOff[7] * 4 + 256);
    int* ptrs[7]; int* csrs[7]; uint2* ceas[7];
    for (int r = 0; r < 7; ++r) {
        int nd = NSn[DST_T_[r]];
        ptrs[r] = (int*)(wsb + off); off = alignup(off + (size_t)(nd + 1) * 4);
    }
    for (int r = 0; r < 7; ++r) {
        csrs[r] = (int*)(wsb + off); off = alignup(off + (size_t)E[r] * 4);
    }
    for (int r = 0; r < 7; ++r) {
        ceas[r] = (uint2*)(wsb + off); off = alignup(off + (size_t)E[r] * 8);
    }

    // ---- batched CSR build ----
    CsrCtx C;
    for (int r = 0; r < 7; ++r) {
        C.src[r] = src[r]; C.dst[r] = dst[r]; C.ea[r] = ea[r];
        C.csr_src[r] = csrs[r]; C.csr_ea[r] = ceas[r]; C.ptr[r] = ptrs[r];
        C.nd[r] = NSn[DST_T_[r]];
    }
    C.deg = deg; C.cursor = cursor; C.bsum = bsum;
    for (int r = 0; r < 8; ++r) { C.eOff[r] = eOff[r]; C.bOff[r] = bOff[r]; }

    hipMemsetAsync(deg, 0, (size_t)bOff[7] * 256 * 4, stream);
    k_hist_all<<<imin((Etot + 255) / 256, 8192), 256, 0, stream>>>(C, Etot);
    k_scan_partial_all<<<bOff[7], 256, 0, stream>>>(C);
    k_scan_mid_all<<<7, 512, 0, stream>>>(C);
    k_scan_final_all<<<bOff[7], 256, 0, stream>>>(C);
    k_scatter_all<<<imin((Etot + 255) / 256, 8192), 256, 0, stream>>>(C, Etot);
    k_wprep<<<1344, 256, 0, stream>>>(W1, W2, wprep, 21 * 16384);

    // ---- input embeddings (bf16 h -> hb0) ----
    for (int t = 0; t < 3; ++t) {
        int n = NSn[t];
        k_input_linear<<<imin((n + 15) / 16, 2048), 128, 0, stream>>>(
            xin[t], linW[t], linb[t], hb0 + (size_t)noff[t] * H, n);
    }

    // ---- layer context ----
    static const int RELS[3][3] = {{0, 2, 0}, {1, 3, 5}, {4, 6, 0}};
    static const int NRELS[3] = {2, 3, 2};
    LayerCtx L;
    int gend = 0;
    for (int t = 0; t < 3; ++t) {
        L.nrel[t] = NRELS[t];
        L.noffH[t] = noff[t] * H;
        L.n[t] = NSn[t];
        gend += (NSn[t] + 127) / 128;
        L.gend[t] = gend;
        for (int k = 0; k < 3; ++k) {
            const int r = RELS[t][k];
            L.ptr[t][k] = ptrs[r];
            L.csr_src[t][k] = csrs[r];
            L.csr_ea[t][k] = ceas[r];
            L.srcOffH[t][k] = noff[SRC_T_[r]] * H;
            L.rel[t][k] = r;
        }
    }

    // ---- layers (hb ping-pong; last layer -> f32 d_out) ----
    unsigned short* hin = hb0;
    unsigned short* hout = hb1;
    for (int l = 0; l < 3; ++l) {
        const int fin = (l == 2) ? 1 : 0;
        k_layer_all<<<L.gend[2], 512, 0, stream>>>(
            L, hin, hout, fout, wprep, eW, ebp, b1, g1, be1, b2, l, fin);
        unsigned short* tmp = hin; hin = hout; hout = tmp;
    }
}

// Round 12
// 842.960 us; speedup vs baseline: 1.4057x; 1.4057x over previous
//
#include <hip/hip_runtime.h>
#include <math.h>

#define H 128

typedef __attribute__((ext_vector_type(8))) short short8;
typedef __attribute__((ext_vector_type(4))) float f32x4;

static const int SRC_T_[7] = {0, 0, 1, 1, 1, 2, 2};
static const int DST_T_[7] = {0, 1, 0, 1, 2, 1, 2};

__device__ __forceinline__ float eluf(float x) {
    return x > 0.f ? x : (__expf(x) - 1.f);
}
__device__ __forceinline__ unsigned short f2bf(float x) {  // RNE f32->bf16
    union { float f; unsigned int u; } v; v.f = x;
    unsigned int r = v.u + 0x7fffu + ((v.u >> 16) & 1u);
    return (unsigned short)(r >> 16);
}
__device__ __forceinline__ float bf2f(unsigned int u) {
    union { unsigned int u; float f; } v; v.u = u << 16;
    return v.f;
}

// async global->LDS, 16 bytes per lane; lds base wave-uniform, gsrc per-lane
#define GLDS16(gp, lp) __builtin_amdgcn_global_load_lds( \
    (const __attribute__((address_space(1))) void*)(gp), \
    (__attribute__((address_space(3))) void*)(lp), 16, 0, 0)

// ---------------------------------------------------------------------------
// Packed preamble: [hist | input-linear x3 | wprep] — mutually independent.
struct PreCtx {
    const int* dst[7];
    int* deg;
    int eOff[8], bOff[8];
    const float* x[3]; const float* linW[3]; const float* linb[3];
    unsigned short* hb[3]; int n[3];
    const float* W1; const float* W2; unsigned short* wp;
    int gHist, gIn[3], gEnd;
};

__global__ __launch_bounds__(256) void k_pre(PreCtx P, int Etot)
{
    __shared__ float Ws[64 * H];          // 32 KB (input branch)
    __shared__ float xs[16 * 64];
    __shared__ unsigned short os[16 * H];
    const int b = blockIdx.x;
    const int tid = threadIdx.x;

    if (b < P.gHist) {                    // ---- histogram ----
        for (int e = b * 256 + tid; e < Etot; e += P.gHist * 256) {
            int r = 0;
            while (e >= P.eOff[r + 1]) ++r;
            atomicAdd(&P.deg[(P.bOff[r] << 8) + P.dst[r][e - P.eOff[r]]], 1);
        }
        return;
    }
    if (b < P.gIn[2]) {                   // ---- input linear ----
        const int t = (b >= P.gIn[0] ? 1 : 0) + (b >= P.gIn[1] ? 1 : 0);
        const int lb = b - (t == 0 ? P.gHist : P.gIn[t - 1]);
        const float* x = P.x[t];
        const float* W = P.linW[t];
        const int n = P.n[t];
        const int j = tid & 127;
        const int half = tid >> 7;
        for (int i = tid; i < 64 * H; i += 256) Ws[i] = W[i];
        const float bj = P.linb[t][j];
        const int r0 = lb * 16;
        const int nrows = min(16, n - r0);
        for (int i = tid; i < nrows * 64; i += 256) xs[i] = x[(size_t)r0 * 64 + i];
        __syncthreads();
        for (int i = half * 8; i < half * 8 + 8; ++i) {
            if (i >= nrows) break;
            float acc = bj;
#pragma unroll
            for (int k = 0; k < 64; k += 4) {
                float4 xv = *(const float4*)&xs[i * 64 + k];
                acc += xv.x * Ws[(k + 0) * H + j] + xv.y * Ws[(k + 1) * H + j]
                     + xv.z * Ws[(k + 2) * H + j] + xv.w * Ws[(k + 3) * H + j];
            }
            os[i * H + j] = f2bf(eluf(acc));
        }
        __syncthreads();
        uint2* d = (uint2*)&P.hb[t][(size_t)r0 * H];
        const uint2* s2 = (const uint2*)os;
        for (int i = tid; i < nrows * 32; i += 256) d[i] = s2[i];
        return;
    }
    {                                     // ---- weight prep ----
        const int lb = b - P.gIn[2];
        const int gw = P.gEnd - P.gIn[2];
        for (int i = lb * 256 + tid; i < 21 * 16384; i += gw * 256) {
            int lr = i >> 14, rem = i & 16383;
            int c = rem >> 7, k = rem & 127;
            P.wp[(size_t)(lr * 2 + 0) * 16384 + rem] = f2bf(P.W1[(size_t)lr * 16384 + k * H + c]);
            P.wp[(size_t)(lr * 2 + 1) * 16384 + rem] = f2bf(P.W2[(size_t)lr * 16384 + k * H + c]);
        }
    }
}

// --------------------------- batched CSR build ------------------------------
struct CsrCtx {
    const int* src[7]; const int* dst[7]; const float* ea[7];
    int* csr_src[7]; uint2* csr_ea[7]; int* ptr[7];
    int* deg; int* cursor; int* bsum;
    int eOff[8];
    int bOff[8];
    int nd[7];
};

__global__ __launch_bounds__(256) void k_scan_partial_all(CsrCtx C)
{
    __shared__ int s[256];
    const int b = blockIdx.x;
    int r = 0;
    while (b >= C.bOff[r + 1]) ++r;
    const int lb = b - C.bOff[r];
    const int tid = threadIdx.x;
    const int idx = lb * 256 + tid;
    s[tid] = idx < C.nd[r] ? C.deg[(C.bOff[r] << 8) + idx] : 0;
    __syncthreads();
    for (int off = 128; off > 0; off >>= 1) {
        if (tid < off) s[tid] += s[tid + off];
        __syncthreads();
    }
    if (tid == 0) C.bsum[b] = s[0];
}

__global__ __launch_bounds__(512) void k_scan_mid_all(CsrCtx C)
{
    __shared__ int s[512];
    const int r = blockIdx.x;
    const int nb = C.bOff[r + 1] - C.bOff[r];
    const int tid = threadIdx.x;
    const int v = tid < nb ? C.bsum[C.bOff[r] + tid] : 0;
    s[tid] = v;
    __syncthreads();
    for (int off = 1; off < 512; off <<= 1) {
        int t = (tid >= off) ? s[tid - off] : 0;
        __syncthreads();
        s[tid] += t;
        __syncthreads();
    }
    if (tid < nb) C.bsum[C.bOff[r] + tid] = s[tid] - v;
    if (tid == nb - 1) C.ptr[r][C.nd[r]] = s[tid];
}

__global__ __launch_bounds__(256) void k_scan_final_all(CsrCtx C)
{
    __shared__ int s[256];
    const int b = blockIdx.x;
    int r = 0;
    while (b >= C.bOff[r + 1]) ++r;
    const int lb = b - C.bOff[r];
    const int tid = threadIdx.x;
    const int idx = lb * 256 + tid;
    const int v = idx < C.nd[r] ? C.deg[(C.bOff[r] << 8) + idx] : 0;
    s[tid] = v;
    __syncthreads();
    for (int off = 1; off < 256; off <<= 1) {
        int t = (tid >= off) ? s[tid - off] : 0;
        __syncthreads();
        s[tid] += t;
        __syncthreads();
    }
    if (idx < C.nd[r]) {
        const int excl = s[tid] - v + C.bsum[b];
        C.ptr[r][idx] = excl;
        C.cursor[(C.bOff[r] << 8) + idx] = excl;
    }
}

__global__ __launch_bounds__(256) void k_scatter_all(CsrCtx C, int Etot)
{
    for (int e = blockIdx.x * 256 + threadIdx.x; e < Etot; e += gridDim.x * 256) {
        int r = 0;
        while (e >= C.eOff[r + 1]) ++r;
        const int le = e - C.eOff[r];
        const int d = C.dst[r][le];
        const int pos = atomicAdd(&C.cursor[(C.bOff[r] << 8) + d], 1);
        C.csr_src[r][pos] = C.src[r][le];
        const float* eap = C.ea[r] + (size_t)3 * le;
        uint2 p;
        p.x = (unsigned int)f2bf(eap[0]) | ((unsigned int)f2bf(eap[1]) << 16);
        p.y = (unsigned int)f2bf(eap[2]);
        C.csr_ea[r][pos] = p;
    }
}

// ---------------------------------------------------------------------------
// Batched gather-aggregate: per-relation block ranges; 4 waves/block;
// wave = 16 consecutive nodes, full wave per node (2 cols/lane).
// 2-stage software pipeline: pair i+2's cs/ce/hv loads fly under pair i's math.
// z written PRE-SWIZZLED: uint index lane ^ ((d&7)<<2).
struct AggCtx {
    const int* ptr[7]; const int* csr_src[7]; const uint2* csr_ea[7];
    const unsigned short* hsrc[7]; const unsigned short* hdst[7];
    unsigned short* z[7];
    int gOff[8];
    int nd[7];
};

__global__ __launch_bounds__(256) void k_aggz_all(
    AggCtx A, const float* __restrict__ eW, const float* __restrict__ eb, int l)
{
    const int b = blockIdx.x;
    int r = 0;
    while (b >= A.gOff[r + 1]) ++r;
    const int lb = b - A.gOff[r];
    const int wave = threadIdx.x >> 6;
    const int lane = threadIdx.x & 63;
    const int t2 = lane << 1;
    const int lr = l * 7 + r;
    const float* eWr = eW + (size_t)lr * 3 * H;
    const float* ebr = eb + (size_t)lr * H;
    const float w00 = eWr[t2],         w01 = eWr[t2 + 1];
    const float w10 = eWr[H + t2],     w11 = eWr[H + t2 + 1];
    const float w20 = eWr[2 * H + t2], w21 = eWr[2 * H + t2 + 1];
    const float b0 = ebr[t2], b1v = ebr[t2 + 1];

    const int nd = A.nd[r];
    const int d0 = lb * 64 + wave * 16;
    if (d0 >= nd) return;
    const int dend = min(d0 + 16, nd);
    const int* __restrict__ ptr = A.ptr[r];
    const int* __restrict__ cs = A.csr_src[r];
    const uint2* __restrict__ ce = A.csr_ea[r];
    const unsigned short* __restrict__ hs = A.hsrc[r];
    const unsigned short* __restrict__ hd = A.hdst[r];
    unsigned int* __restrict__ zp = (unsigned int*)A.z[r];

    int p1 = ptr[d0];
    for (int d = d0; d < dend; ++d) {
        const int p0v = p1;
        p1 = ptr[d + 1];
        const unsigned int hdv = ((const unsigned int*)&hd[(size_t)d * H])[lane];
        float acc0 = bf2f(hdv & 0xffffu);
        float acc1 = bf2f(hdv >> 16);
        int i = p0v;
        if (i + 1 < p1) {
            // pipeline prologue: current pair's operands
            int s0 = cs[i], s1 = cs[i + 1];
            uint2 eC0 = ce[i], eC1 = ce[i + 1];
            unsigned int hvC0 = ((const unsigned int*)&hs[(size_t)s0 * H])[lane];
            unsigned int hvC1 = ((const unsigned int*)&hs[(size_t)s1 * H])[lane];
            for (;;) {
                const int jn = i + 2;
                const bool more = (jn + 1 < p1);
                uint2 eN0, eN1; unsigned int hvN0 = 0, hvN1 = 0;
                if (more) {  // issue next pair's loads before current math
                    const int sN0 = cs[jn], sN1 = cs[jn + 1];
                    eN0 = ce[jn]; eN1 = ce[jn + 1];
                    hvN0 = ((const unsigned int*)&hs[(size_t)sN0 * H])[lane];
                    hvN1 = ((const unsigned int*)&hs[(size_t)sN1 * H])[lane];
                }
                const float a00 = bf2f(eC0.x & 0xffffu), a01 = bf2f(eC0.x >> 16), a02 = bf2f(eC0.y & 0xffffu);
                const float a10 = bf2f(eC1.x & 0xffffu), a11 = bf2f(eC1.x >> 16), a12 = bf2f(eC1.y & 0xffffu);
                acc0 += fmaxf(bf2f(hvC0 & 0xffffu) + a00 * w00 + a01 * w10 + a02 * w20 + b0, 0.f)
                      + fmaxf(bf2f(hvC1 & 0xffffu) + a10 * w00 + a11 * w10 + a12 * w20 + b0, 0.f);
                acc1 += fmaxf(bf2f(hvC0 >> 16) + a00 * w01 + a01 * w11 + a02 * w21 + b1v, 0.f)
                      + fmaxf(bf2f(hvC1 >> 16) + a10 * w01 + a11 * w11 + a12 * w21 + b1v, 0.f);
                i = jn;
                if (!more) break;
                eC0 = eN0; eC1 = eN1; hvC0 = hvN0; hvC1 = hvN1;
            }
        }
        if (i < p1) {  // odd tail
            const int s = cs[i];
            const uint2 ep = ce[i];
            const float a0 = bf2f(ep.x & 0xffffu);
            const float a1 = bf2f(ep.x >> 16);
            const float a2 = bf2f(ep.y & 0xffffu);
            const unsigned int hv = ((const unsigned int*)&hs[(size_t)s * H])[lane];
            acc0 += fmaxf(bf2f(hv & 0xffffu) + a0 * w00 + a1 * w10 + a2 * w20 + b0, 0.f);
            acc1 += fmaxf(bf2f(hv >> 16)     + a0 * w01 + a1 * w11 + a2 * w21 + b1v, 0.f);
        }
        zp[(size_t)d * 64 + (lane ^ ((d & 7) << 2))] =
            (unsigned int)f2bf(acc0) | ((unsigned int)f2bf(acc1) << 16);
    }
}

// ---------------------------------------------------------------------------
// One dispatch per layer: all 3 dst-types' fused MLPs.
// z pre-swizzled in global; staged via global_load_lds; next relation's
// staging issued after the a1t barrier (flies under GEMM2).
struct MlpCtx {
    const unsigned short* z[3][3];
    int lr[3][3];
    int nrel[3];
    int gend[3];
    int noffH[3];
    int n[3];
};

__global__ __launch_bounds__(512, 4) void k_mlp_all(
    MlpCtx M, const unsigned short* __restrict__ hb,
    unsigned short* __restrict__ hbw, float* __restrict__ fout,
    const unsigned short* __restrict__ wprep,
    const float* __restrict__ b1g, const float* __restrict__ g1g,
    const float* __restrict__ be1g, const float* __restrict__ b2g, int fin)
{
    __shared__ unsigned short zt[128 * H];   // 32 KB, holds pre-swizzled rows
    __shared__ unsigned short a1t[128 * H];  // 32 KB, XOR-swizzled

    const int b = blockIdx.x;
    const int t = (b >= M.gend[0] ? 1 : 0) + (b >= M.gend[1] ? 1 : 0);
    const int lb = b - (t == 0 ? 0 : M.gend[t - 1]);
    const int n = M.n[t];
    const int nrel = M.nrel[t];
    const unsigned short* hbp = hb + (size_t)M.noffH[t];

    const int tid = threadIdx.x;
    const int lane = tid & 63;
    const int wave = tid >> 6;
    const int wr = wave >> 2;
    const int wc = wave & 3;
    const int l15 = lane & 15;
    const int lq  = lane >> 4;
    const int c0 = wc * 32 + l15;

    const int r0 = lb * 128;
    const int rows = min(128, n - r0);
    const bool full = (rows == 128);

    auto stage = [&](const unsigned short* z) {
        const unsigned short* zsrc = z + (size_t)r0 * H;
        if (full) {
#pragma unroll
            for (int it = 0; it < 4; ++it) {
                const int off = (wave * 4 + it) * 512;
                GLDS16(zsrc + off + lane * 8, zt + off);
            }
        } else {
            for (int idx = tid; idx < rows * 16; idx += 512) {
                *(uint4*)&zt[idx * 8] = *(const uint4*)&zsrc[idx * 8];
            }
        }
    };

    const float bn_inv = 0.99999500003749977f;
    const f32x4 Z4 = {0.f, 0.f, 0.f, 0.f};
    f32x4 acc2[4][2];
#pragma unroll
    for (int rb = 0; rb < 4; ++rb)
#pragma unroll
        for (int nf = 0; nf < 2; ++nf) acc2[rb][nf] = Z4;
    float b2s0 = 0.f, b2s1 = 0.f;

    stage(M.z[t][0]);

    for (int rl = 0; rl < nrel; ++rl) {
        const int lr = M.lr[t][rl];
        const unsigned short* wp = wprep + (size_t)lr * 32768;
        short8 w1f[2][4];
#pragma unroll
        for (int nf = 0; nf < 2; ++nf)
#pragma unroll
            for (int kc = 0; kc < 4; ++kc)
                w1f[nf][kc] = *(const short8*)&wp[(c0 + nf * 16) * H + kc * 32 + (lq << 3)];
        const float b1c0 = b1g[lr * H + c0],            b1c1 = b1g[lr * H + c0 + 16];
        const float sc0  = g1g[lr * H + c0] * bn_inv,   sc1  = g1g[lr * H + c0 + 16] * bn_inv;
        const float be0  = be1g[lr * H + c0],           be1v = be1g[lr * H + c0 + 16];
        b2s0 += b2g[lr * H + c0]; b2s1 += b2g[lr * H + c0 + 16];

        __syncthreads();  // A: drains staging -> zt ready

        f32x4 acc1[4][2];
#pragma unroll
        for (int rb = 0; rb < 4; ++rb)
#pragma unroll
            for (int nf = 0; nf < 2; ++nf) acc1[rb][nf] = Z4;
#pragma unroll
        for (int kc = 0; kc < 4; ++kc) {
            const int kb = kc * 32 + (lq << 3);
            short8 af[4];
#pragma unroll
            for (int rb = 0; rb < 4; ++rb) {
                const int row = wr * 64 + rb * 16 + l15;
                af[rb] = *(const short8*)&zt[row * H + (kb ^ ((row & 7) << 3))];
            }
#pragma unroll
            for (int rb = 0; rb < 4; ++rb)
#pragma unroll
                for (int nf = 0; nf < 2; ++nf)
                    acc1[rb][nf] = __builtin_amdgcn_mfma_f32_16x16x32_bf16(
                        af[rb], w1f[nf][kc], acc1[rb][nf], 0, 0, 0);
        }
#pragma unroll
        for (int rb = 0; rb < 4; ++rb)
#pragma unroll
            for (int nf = 0; nf < 2; ++nf) {
                const int col = c0 + nf * 16;
                const float b1c = nf == 0 ? b1c0 : b1c1;
                const float scv = nf == 0 ? sc0 : sc1;
                const float bev = nf == 0 ? be0 : be1v;
#pragma unroll
                for (int rg = 0; rg < 4; ++rg) {
                    const int row = wr * 64 + rb * 16 + (lq << 2) + rg;
                    float v = fmaxf((acc1[rb][nf][rg] + b1c) * scv + bev, 0.f);
                    a1t[row * H + (col ^ ((row & 7) << 3))] = f2bf(v);
                }
            }
        __syncthreads();  // B: a1t ready; zt dead

        if (rl + 1 < nrel) stage(M.z[t][rl + 1]);

#pragma unroll
        for (int kc = 0; kc < 4; ++kc) {
            const int kb = kc * 32 + (lq << 3);
            short8 af[4], wf[2];
#pragma unroll
            for (int rb = 0; rb < 4; ++rb) {
                const int row = wr * 64 + rb * 16 + l15;
                af[rb] = *(const short8*)&a1t[row * H + (kb ^ ((row & 7) << 3))];
            }
#pragma unroll
            for (int nf = 0; nf < 2; ++nf)
                wf[nf] = *(const short8*)&wp[16384 + (c0 + nf * 16) * H + kb];
#pragma unroll
            for (int rb = 0; rb < 4; ++rb)
#pragma unroll
                for (int nf = 0; nf < 2; ++nf)
                    acc2[rb][nf] = __builtin_amdgcn_mfma_f32_16x16x32_bf16(
                        af[rb], wf[nf], acc2[rb][nf], 0, 0, 0);
        }
    }

    if (fin) {
        float* foutp = fout + (size_t)M.noffH[t];
#pragma unroll
        for (int rb = 0; rb < 4; ++rb)
#pragma unroll
            for (int nf = 0; nf < 2; ++nf) {
                const int col = c0 + nf * 16;
                const float b2s = nf == 0 ? b2s0 : b2s1;
#pragma unroll
                for (int rg = 0; rg < 4; ++rg) {
                    const int row = wr * 64 + rb * 16 + (lq << 2) + rg;
                    if (row < rows) {
                        const size_t o = (size_t)(r0 + row) * H + col;
                        foutp[o] = eluf(acc2[rb][nf][rg] + b2s
                                        + bf2f((unsigned int)hbp[o]));
                    }
                }
            }
    } else {
        unsigned short* hbwp = hbw + (size_t)M.noffH[t];
        __syncthreads();
#pragma unroll
        for (int rb = 0; rb < 4; ++rb)
#pragma unroll
            for (int nf = 0; nf < 2; ++nf) {
                const int col = c0 + nf * 16;
                const float b2s = nf == 0 ? b2s0 : b2s1;
#pragma unroll
                for (int rg = 0; rg < 4; ++rg) {
                    const int row = wr * 64 + rb * 16 + (lq << 2) + rg;
                    if (row < rows) {
                        const size_t o = (size_t)(r0 + row) * H + col;
                        a1t[row * H + col] = f2bf(eluf(acc2[rb][nf][rg] + b2s
                                                       + bf2f((unsigned int)hbp[o])));
                    }
                }
            }
        __syncthreads();
        uint2* d = (uint2*)&hbwp[(size_t)r0 * H];
        const uint2* s2 = (const uint2*)a1t;
        for (int idx = tid; idx < rows * 32; idx += 512) d[idx] = s2[idx];
    }
}

static inline int imin(int a, int b) { return a < b ? a : b; }
static inline size_t alignup(size_t x) { return (x + 255) & ~(size_t)255; }

extern "C" void kernel_launch(void* const* d_in, const int* in_sizes, int n_in,
                              void* d_out, int out_size, void* d_ws, size_t ws_size,
                              hipStream_t stream) {
    const float* xin[3] = {(const float*)d_in[0], (const float*)d_in[1], (const float*)d_in[2]};
    const int* src[7]; const int* dst[7]; const float* ea[7]; int E[7];
    for (int r = 0; r < 7; ++r) {
        src[r] = (const int*)d_in[3 + 3 * r];
        dst[r] = (const int*)d_in[4 + 3 * r];
        ea[r]  = (const float*)d_in[5 + 3 * r];
        E[r]   = in_sizes[3 + 3 * r];
    }
    const float* linW[3] = {(const float*)d_in[24], (const float*)d_in[26], (const float*)d_in[28]};
    const float* linb[3] = {(const float*)d_in[25], (const float*)d_in[27], (const float*)d_in[29]};
    const float* eW  = (const float*)d_in[30];
    const float* ebp = (const float*)d_in[31];
    const float* W1  = (const float*)d_in[32];
    const float* b1  = (const float*)d_in[33];
    const float* g1  = (const float*)d_in[34];
    const float* be1 = (const float*)d_in[35];
    const float* W2  = (const float*)d_in[36];
    const float* b2  = (const float*)d_in[37];

    const int NSn[3]  = {in_sizes[0] / 64, in_sizes[1] / 64, in_sizes[2] / 64};
    const int NTOT = NSn[0] + NSn[1] + NSn[2];
    const int noff[3] = {0, NSn[0], NSn[0] + NSn[1]};

    float* fout = (float*)d_out;

    // prefixes
    int eOff[8]; eOff[0] = 0;
    for (int r = 0; r < 7; ++r) eOff[r + 1] = eOff[r] + E[r];
    const int Etot = eOff[7];
    int bOff[8]; bOff[0] = 0;
    for (int r = 0; r < 7; ++r) bOff[r + 1] = bOff[r] + (NSn[DST_T_[r]] + 255) / 256;
    int gOff[8]; gOff[0] = 0;
    for (int r = 0; r < 7; ++r) gOff[r + 1] = gOff[r] + (NSn[DST_T_[r]] + 63) / 64;

    // workspace carve-up
    char* wsb = (char*)d_ws;
    size_t off = 0;
    unsigned short* hb = (unsigned short*)(wsb + off); off = alignup(off + (size_t)NTOT * H * 2);
    unsigned short* zb[7];
    for (int r = 0; r < 7; ++r) {
        int nd = NSn[DST_T_[r]];
        zb[r] = (unsigned short*)(wsb + off); off = alignup(off + (size_t)nd * H * 2);
    }
    unsigned short* wprep = (unsigned short*)(wsb + off); off = alignup(off + (size_t)21 * 32768 * 2);
    int* deg    = (int*)(wsb + off); off = alignup(off + (size_t)bOff[7] * 256 * 4);
    int* cursor = (int*)(wsb + off); off = alignup(off + (size_t)bOff[7] * 256 * 4);
    int* bsum   = (int*)(wsb + off); off = alignup(off + (size_t)bOff[7] * 4 + 256);
    int* ptrs[7]; int* csrs[7]; uint2* ceas[7];
    for (int r = 0; r < 7; ++r) {
        int nd = NSn[DST_T_[r]];
        ptrs[r] = (int*)(wsb + off); off = alignup(off + (size_t)(nd + 1) * 4);
    }
    for (int r = 0; r < 7; ++r) {
        csrs[r] = (int*)(wsb + off); off = alignup(off + (size_t)E[r] * 4);
    }
    for (int r = 0; r < 7; ++r) {
        ceas[r] = (uint2*)(wsb + off); off = alignup(off + (size_t)E[r] * 8);
    }

    // ---- packed preamble ----
    PreCtx P;
    for (int r = 0; r < 7; ++r) P.dst[r] = dst[r];
    P.deg = deg;
    for (int r = 0; r < 8; ++r) { P.eOff[r] = eOff[r]; P.bOff[r] = bOff[r]; }
    for (int t = 0; t < 3; ++t) {
        P.x[t] = xin[t]; P.linW[t] = linW[t]; P.linb[t] = linb[t];
        P.hb[t] = hb + (size_t)noff[t] * H; P.n[t] = NSn[t];
    }
    P.W1 = W1; P.W2 = W2; P.wp = wprep;
    P.gHist = 1024;
    int g = P.gHist;
    for (int t = 0; t < 3; ++t) { g += (NSn[t] + 15) / 16; P.gIn[t] = g; }
    P.gEnd = g + 336;

    hipMemsetAsync(deg, 0, (size_t)bOff[7] * 256 * 4, stream);
    k_pre<<<P.gEnd, 256, 0, stream>>>(P, Etot);

    // ---- CSR scans + scatter ----
    CsrCtx C;
    for (int r = 0; r < 7; ++r) {
        C.src[r] = src[r]; C.dst[r] = dst[r]; C.ea[r] = ea[r];
        C.csr_src[r] = csrs[r]; C.csr_ea[r] = ceas[r]; C.ptr[r] = ptrs[r];
        C.nd[r] = NSn[DST_T_[r]];
    }
    C.deg = deg; C.cursor = cursor; C.bsum = bsum;
    for (int r = 0; r < 8; ++r) { C.eOff[r] = eOff[r]; C.bOff[r] = bOff[r]; }

    k_scan_partial_all<<<bOff[7], 256, 0, stream>>>(C);
    k_scan_mid_all<<<7, 512, 0, stream>>>(C);
    k_scan_final_all<<<bOff[7], 256, 0, stream>>>(C);
    k_scatter_all<<<imin((Etot + 255) / 256, 8192), 256, 0, stream>>>(C, Etot);

    // ---- agg context ----
    AggCtx A;
    for (int r = 0; r < 7; ++r) {
        A.ptr[r] = ptrs[r]; A.csr_src[r] = csrs[r]; A.csr_ea[r] = ceas[r];
        A.hsrc[r] = hb + (size_t)noff[SRC_T_[r]] * H;
        A.hdst[r] = hb + (size_t)noff[DST_T_[r]] * H;
        A.z[r] = zb[r];
        A.nd[r] = NSn[DST_T_[r]];
    }
    for (int r = 0; r < 8; ++r) A.gOff[r] = gOff[r];

    // ---- mlp context ----
    static const int RELS[3][3] = {{0, 2, 0}, {1, 3, 5}, {4, 6, 0}};
    static const int NRELS[3] = {2, 3, 2};
    MlpCtx M;
    int gend = 0;
    for (int t = 0; t < 3; ++t) {
        M.nrel[t] = NRELS[t];
        M.noffH[t] = noff[t] * H;
        M.n[t] = NSn[t];
        gend += (NSn[t] + 127) / 128;
        M.gend[t] = gend;
        for (int k = 0; k < 3; ++k) M.z[t][k] = zb[RELS[t][k]];
    }

    // ---- layers ----
    for (int l = 0; l < 3; ++l) {
        const int fin = (l == 2) ? 1 : 0;
        k_aggz_all<<<gOff[7], 256, 0, stream>>>(A, eW, ebp, l);
        for (int t = 0; t < 3; ++t)
            for (int k = 0; k < 3; ++k) M.lr[t][k] = l * 7 + RELS[t][k];
        k_mlp_all<<<M.gend[2], 512, 0, stream>>>(
            M, hb, hb, fout, wprep, b1, g1, be1, b2, fin);
    }
}